// Round 19
// baseline (184.159 us; speedup 1.0000x reference)
//
#include <hip/hip_runtime.h>
#include <hip/hip_cooperative_groups.h>

namespace cg = cooperative_groups;

// RankingLoss = mean over rows of sum_{pairs: lab_a-lab_b > TOL} lsig(lg_a-lg_b)
//
// Single cooperative kernel (1 graph node), 3 phases split by grid.sync():
//  P1: per-row bucket-major reorder (width TOL): two-pass LDS scatter ->
//      coalesced export of g_labs(lab,s) and g_EC(E=2^s, C-bits).
//  P2: 1792 work items, block-strided:
//      items 0..511   side: pairs C_i<=j<i (bucket dist<=1): exact |ld|>TOL
//        mask; p *= valid?(Ei+Ej):1 (log per 8), accS -= valid? s_hi.
//      items 512..1791 tile: 512i x 256j, j<C_i guaranteed-valid region:
//        t=Ej*invEi; p=fma(t,p,p); 2 logs/16 pairs; per-thread trip bound.
//  P3: block 0 reduces 1792 f32 partials (double), out = -ln2/B * total.
// All math identical to r15 (27.1us, absmax 0.0); this round tests the
// fixed-per-graph-node-overhead hypothesis (~3.3us/node).

#define NN 2048
#define BB 64
#define TOLF 0.01f
#define BLK 256
#define NTILE 20
#define TILEBLKS (BB * NTILE)            // 1280
#define SIDEBLKS (BB * 8)                // 512
#define WGRID (TILEBLKS + SIDEBLKS)      // 1792
#define SWIN 448
#define LOG2E 1.4426950408889634f

__device__ float2 g_labs[BB][NN];  // (label, s) bucket-major
__device__ float2 g_EC[BB][NN];    // (E = 2^s, C-as-int-bits)
__device__ float  g_part[WGRID];

#define SMEM_BYTES 17600

__global__ __launch_bounds__(BLK) void rank_all(const float* __restrict__ logits,
                                                const float* __restrict__ labels,
                                                float* __restrict__ out) {
    cg::grid_group grid = cg::this_grid();
    __shared__ __align__(16) char smem[SMEM_BYTES];
    const int bid = blockIdx.x, tid = threadIdx.x;
    const int nblk = gridDim.x;

    // ---------------- P1: bucket reorder (block-strided rows) ----------------
    {
        float2* st  = (float2*)smem;             // [2048] 16 KB
        int* cnt  = (int*)(smem + 16384);        // [100]
        int* offs = cnt + 100;                   // [100]
        int* pref = offs + 100;                  // [101]
        int* wtot = pref + 101;
        for (int row = bid; row < BB; row += nblk) {
            __syncthreads();
            const float* lg = logits + (size_t)row * NN;
            const float* lb = labels + (size_t)row * NN;
            for (int x = tid; x < 100; x += BLK) { cnt[x] = 0; offs[x] = 0; }
            __syncthreads();
            float la8[8], lg8[8];
            int   p8[8];
#pragma unroll
            for (int q = 0; q < 8; ++q) {
                int x = tid + q * BLK;
                la8[q] = lb[x];
                lg8[q] = lg[x];
                atomicAdd(&cnt[min(99, (int)(la8[q] * 100.0f))], 1);
            }
            __syncthreads();
            {   // wave-parallel exclusive prefix over 100 counts (2 waves)
                int v = (tid < 100) ? cnt[tid] : 0;
                int x = v;
#pragma unroll
                for (int o = 1; o < 64; o <<= 1) {
                    int y = __shfl_up(x, o);
                    if ((tid & 63) >= o) x += y;
                }
                if (tid == 63) *wtot = x;
                __syncthreads();
                if (tid >= 64 && tid < 128) x += *wtot;
                if (tid < 101) pref[tid] = x - v;
            }
            __syncthreads();
            // pass A: scatter (lab, s); export g_labs
#pragma unroll
            for (int q = 0; q < 8; ++q) {
                int b = min(99, (int)(la8[q] * 100.0f));
                p8[q] = pref[b] + atomicAdd(&offs[b], 1);
                st[p8[q]] = make_float2(la8[q], lg8[q] * LOG2E);
            }
            __syncthreads();
            for (int x = tid; x < NN; x += BLK) g_labs[row][x] = st[x];
            __syncthreads();
            // pass B: scatter (E, C-bits); export g_EC
#pragma unroll
            for (int q = 0; q < 8; ++q) {
                int b = min(99, (int)(la8[q] * 100.0f));
                float s = lg8[q] * LOG2E;
                st[p8[q]] = make_float2(__builtin_amdgcn_exp2f(s),
                                        __int_as_float((b >= 1) ? pref[b - 1] : 0));
            }
            __syncthreads();
            for (int x = tid; x < NN; x += BLK) g_EC[row][x] = st[x];
        }
    }
    grid.sync();

    // ---------------- P2: work items (block-strided) ----------------
    for (int item = bid; item < WGRID; item += nblk) {
        __syncthreads();                           // smem reuse fence
        float accB = 0.0f;                         // block partial (log2 units)
        if (item < SIDEBLKS) {
            float2* sLS = (float2*)smem;           // [448]
            float*  sE  = (float*)(smem + 3584);   // [448]
            int*    sCs = (int*)(smem + 5400);
            float*  swv = (float*)(smem + 5408);   // [4]
            const int row = item >> 3;
            const int c0  = (item & 7) << 8;
            if (tid == 0) *sCs = __float_as_int(g_EC[row][c0].y);
            __syncthreads();
            const int Cs  = *sCs;
            const int len = c0 + 256 - Cs;
            for (int x = tid; x < len; x += BLK) {
                sLS[x] = g_labs[row][Cs + x];
                sE[x]  = g_EC[row][Cs + x].x;
            }
            __syncthreads();

            const int i = c0 + tid;
            const float2 lsi = g_labs[row][i];
            const float lai = lsi.x, si = lsi.y;
            const float2 eci = g_EC[row][i];
            const float Ei  = eci.x;
            const int wloc  = __float_as_int(eci.y) - Cs;
            const int iloc  = i - Cs;

            float accL = 0.0f, accS = 0.0f;
            float p = 1.0f;
            int cnt8 = 0;
            for (int j = wloc; j < iloc; ++j) {
                float2 ls = sLS[j];
                float ld = lai - ls.x;
                bool valid = fabsf(ld) > TOLF;     // exact reference predicate
                float term = valid ? (Ei + sE[j]) : 1.0f;
                p *= term;
                if (++cnt8 == 8) { accL += __builtin_amdgcn_logf(p); p = 1.0f; cnt8 = 0; }
                float sh = (ld > 0.0f) ? si : ls.y;
                accS -= valid ? sh : 0.0f;
            }
            accL += __builtin_amdgcn_logf(p);

            float v = accL + accS;
            for (int off = 32; off > 0; off >>= 1) v += __shfl_down(v, off);
            if ((tid & 63) == 0) swv[tid >> 6] = v;
            __syncthreads();
            accB = swv[0] + swv[1] + swv[2] + swv[3];
        } else {
            float* swin  = (float*)smem;           // [256]
            float* swave = (float*)(smem + 1024);  // [4]
            const int tb = item - SIDEBLKS;
            const int row = tb / NTILE;
            const int t = tb % NTILE;
            const int it = (t < 2) ? 0 : (t < 6) ? 1 : (t < 12) ? 2 : 3;
            const int jt = t - it * (it + 1);
            const int ibeg = it * 512, jbeg = jt * 256;

            float accL = 0.0f;
            const int Cmax = __float_as_int(g_EC[row][ibeg + 511].y);
            if (jbeg < Cmax) {
                swin[tid] = g_EC[row][jbeg + tid].x;
                __syncthreads();
                const int ia = ibeg + tid;
                const int ib = ia + 256;
                const float2 eca = g_EC[row][ia];
                const float2 ecb = g_EC[row][ib];
                const float invEa = __builtin_amdgcn_rcpf(eca.x);
                const float invEb = __builtin_amdgcn_rcpf(ecb.x);
                int tripa = max(0, min(256, __float_as_int(eca.y) - jbeg));
                int tripb = max(0, min(256, __float_as_int(ecb.y) - jbeg));
                const int m16a = tripa & ~15;
                const int m16b = tripb & ~15;

                for (int jj = 0; jj < m16a; jj += 16) {
                    const float4* q = (const float4*)&swin[jj];
                    float4 w0 = q[0], w1 = q[1], w2 = q[2], w3 = q[3];
                    float pa0 = 1.0f, pa1 = 1.0f, pb0 = 1.0f, pb1 = 1.0f;
                    pa0 = fmaf(w0.x * invEa, pa0, pa0); pb0 = fmaf(w0.x * invEb, pb0, pb0);
                    pa0 = fmaf(w0.y * invEa, pa0, pa0); pb0 = fmaf(w0.y * invEb, pb0, pb0);
                    pa0 = fmaf(w0.z * invEa, pa0, pa0); pb0 = fmaf(w0.z * invEb, pb0, pb0);
                    pa0 = fmaf(w0.w * invEa, pa0, pa0); pb0 = fmaf(w0.w * invEb, pb0, pb0);
                    pa1 = fmaf(w1.x * invEa, pa1, pa1); pb1 = fmaf(w1.x * invEb, pb1, pb1);
                    pa1 = fmaf(w1.y * invEa, pa1, pa1); pb1 = fmaf(w1.y * invEb, pb1, pb1);
                    pa1 = fmaf(w1.z * invEa, pa1, pa1); pb1 = fmaf(w1.z * invEb, pb1, pb1);
                    pa1 = fmaf(w1.w * invEa, pa1, pa1); pb1 = fmaf(w1.w * invEb, pb1, pb1);
                    pa0 = fmaf(w2.x * invEa, pa0, pa0); pb0 = fmaf(w2.x * invEb, pb0, pb0);
                    pa0 = fmaf(w2.y * invEa, pa0, pa0); pb0 = fmaf(w2.y * invEb, pb0, pb0);
                    pa0 = fmaf(w2.z * invEa, pa0, pa0); pb0 = fmaf(w2.z * invEb, pb0, pb0);
                    pa0 = fmaf(w2.w * invEa, pa0, pa0); pb0 = fmaf(w2.w * invEb, pb0, pb0);
                    pa1 = fmaf(w3.x * invEa, pa1, pa1); pb1 = fmaf(w3.x * invEb, pb1, pb1);
                    pa1 = fmaf(w3.y * invEa, pa1, pa1); pb1 = fmaf(w3.y * invEb, pb1, pb1);
                    pa1 = fmaf(w3.z * invEa, pa1, pa1); pb1 = fmaf(w3.z * invEb, pb1, pb1);
                    pa1 = fmaf(w3.w * invEa, pa1, pa1); pb1 = fmaf(w3.w * invEb, pb1, pb1);
                    accL += __builtin_amdgcn_logf(pa0) + __builtin_amdgcn_logf(pa1)
                          + __builtin_amdgcn_logf(pb0) + __builtin_amdgcn_logf(pb1);
                }
                for (int jj = m16a; jj < m16b; jj += 16) {
                    const float4* q = (const float4*)&swin[jj];
                    float4 w0 = q[0], w1 = q[1], w2 = q[2], w3 = q[3];
                    float pb0 = 1.0f, pb1 = 1.0f;
                    pb0 = fmaf(w0.x * invEb, pb0, pb0);
                    pb0 = fmaf(w0.y * invEb, pb0, pb0);
                    pb0 = fmaf(w0.z * invEb, pb0, pb0);
                    pb0 = fmaf(w0.w * invEb, pb0, pb0);
                    pb1 = fmaf(w1.x * invEb, pb1, pb1);
                    pb1 = fmaf(w1.y * invEb, pb1, pb1);
                    pb1 = fmaf(w1.z * invEb, pb1, pb1);
                    pb1 = fmaf(w1.w * invEb, pb1, pb1);
                    pb0 = fmaf(w2.x * invEb, pb0, pb0);
                    pb0 = fmaf(w2.y * invEb, pb0, pb0);
                    pb0 = fmaf(w2.z * invEb, pb0, pb0);
                    pb0 = fmaf(w2.w * invEb, pb0, pb0);
                    pb1 = fmaf(w3.x * invEb, pb1, pb1);
                    pb1 = fmaf(w3.y * invEb, pb1, pb1);
                    pb1 = fmaf(w3.z * invEb, pb1, pb1);
                    pb1 = fmaf(w3.w * invEb, pb1, pb1);
                    accL += __builtin_amdgcn_logf(pb0) + __builtin_amdgcn_logf(pb1);
                }
                if (m16a < tripa) {
                    float p0 = 1.0f, p1 = 1.0f;
#pragma unroll
                    for (int u = 0; u < 8; ++u) {
                        float t0 = (m16a + u     < tripa) ? fmaf(swin[m16a + u],     invEa, 1.0f) : 1.0f;
                        float t1 = (m16a + 8 + u < tripa) ? fmaf(swin[m16a + 8 + u], invEa, 1.0f) : 1.0f;
                        p0 *= t0; p1 *= t1;
                    }
                    accL += __builtin_amdgcn_logf(p0) + __builtin_amdgcn_logf(p1);
                }
                if (m16b < tripb) {
                    float p0 = 1.0f, p1 = 1.0f;
#pragma unroll
                    for (int u = 0; u < 8; ++u) {
                        float t0 = (m16b + u     < tripb) ? fmaf(swin[m16b + u],     invEb, 1.0f) : 1.0f;
                        float t1 = (m16b + 8 + u < tripb) ? fmaf(swin[m16b + 8 + u], invEb, 1.0f) : 1.0f;
                        p0 *= t0; p1 *= t1;
                    }
                    accL += __builtin_amdgcn_logf(p0) + __builtin_amdgcn_logf(p1);
                }
            }
            float v = accL;
            for (int off = 32; off > 0; off >>= 1) v += __shfl_down(v, off);
            if ((tid & 63) == 0) swave[tid >> 6] = v;
            __syncthreads();
            accB = swave[0] + swave[1] + swave[2] + swave[3];
        }
        if (tid == 0) g_part[item] = accB;
    }
    grid.sync();

    // ---------------- P3: final reduce (block 0) ----------------
    if (bid == 0) {
        double acc = 0.0;
        for (int idx = tid; idx < WGRID; idx += BLK) acc += (double)g_part[idx];
        for (int off = 32; off > 0; off >>= 1) acc += __shfl_down(acc, off);
        double* sw = (double*)smem;
        __syncthreads();
        if ((tid & 63) == 0) sw[tid >> 6] = acc;
        __syncthreads();
        if (tid == 0)
            out[0] = (float)((sw[0] + sw[1] + sw[2] + sw[3]) *
                             (-0.6931471805599453 / (double)BB));
    }
}

extern "C" void kernel_launch(void* const* d_in, const int* in_sizes, int n_in,
                              void* d_out, int out_size, void* d_ws, size_t ws_size,
                              hipStream_t stream) {
    const float* logits = (const float*)d_in[0];
    const float* labels = (const float*)d_in[1];
    float* out = (float*)d_out;
    (void)in_sizes; (void)n_in; (void)out_size; (void)d_ws; (void)ws_size;

    int maxb = 0;
    hipOccupancyMaxActiveBlocksPerMultiprocessor(&maxb, rank_all, BLK, 0);
    if (maxb < 1) maxb = 1;
    int grid = maxb * 256;                // 256 CUs on MI355X
    if (grid > WGRID) grid = WGRID;

    void* args[] = { (void*)&logits, (void*)&labels, (void*)&out };
    hipLaunchCooperativeKernel((const void*)rank_all, dim3(grid), dim3(BLK),
                               args, 0, stream);
}

// Round 20
// 34.837 us; speedup vs baseline: 5.2864x; 5.2864x over previous
//
#include <hip/hip_runtime.h>
#include <math.h>

// RankingLoss = mean over rows of sum_{pairs: lab_a-lab_b > TOL} lsig(lg_a-lg_b)
//
// lsig(x) = -ln2*log2(1 + 2^{s_lo - s_hi}),  s = logit*log2e,  E = 2^s.
// Rows reordered bucket-major by label (bucket width = TOL). For j < C_i
// (C_i = start of bucket b_i-1) pair guaranteed valid, i = high:
//   tile core: t = E_j*invE_i; p = fma(t,p,p); v_log per 8; 512i x 256j tiles.
// Side pairs (C_i <= j < i): |ld|>TOL mask; (Ei+Ej) product + accS -= s_hi;
//   LDS-staged window; side blocks FIRST in grid.  (r15-proven, 27.1 us)
// r20 change (single variable): rank_pre split into two FULLY PARALLEL
// kernels — K_hist (64 blk: histogram+prefix, ~1us) and K_scatter (512 blk:
// one global-atomic placement per element + scattered export, TLP-hidden).
// The old pre ran 3 dependent barrier-passes at 1 block/CU (192 CUs idle).

#define NN 2048
#define BB 64
#define TOLF 0.01f
#define BLK 256
#define NTILE 20                         // i-tiles of 512: offsets it*(it+1)
#define TILEBLKS (BB * NTILE)            // 1280
#define SIDEBLKS (BB * 8)                // 512
#define WGRID (TILEBLKS + SIDEBLKS)      // 1792
#define SWIN 448                         // side LDS window capacity
#define LOG2E 1.4426950408889634f

__device__ float2 g_labs[BB][NN];  // (label, s) bucket-major
__device__ float  g_Es[BB][NN];    // 2^s = e^logit
__device__ int    g_C[BB][NN];     // start of bucket b_i - 1
__device__ int    g_pref[BB][101]; // bucket start offsets
__device__ int    g_offs[BB][100]; // atomic placement cursors
__device__ float  g_part[TILEBLKS];
__device__ double g_partS[SIDEBLKS];

// ---------------- K_hist: histogram + prefix (64 blocks, tiny) ----------------
__global__ __launch_bounds__(BLK) void rank_hist(const float* __restrict__ labels) {
    __shared__ int cnt[100];
    __shared__ int wtot;
    const int row = blockIdx.x, tid = threadIdx.x;
    const float* lb = labels + (size_t)row * NN;
    for (int x = tid; x < 100; x += BLK) cnt[x] = 0;
    __syncthreads();
    for (int x = tid; x < NN; x += BLK)
        atomicAdd(&cnt[min(99, (int)(lb[x] * 100.0f))], 1);
    __syncthreads();
    {   // wave-parallel exclusive prefix over 100 counts (waves 0-1)
        int v = (tid < 100) ? cnt[tid] : 0;
        int x = v;
#pragma unroll
        for (int o = 1; o < 64; o <<= 1) {
            int y = __shfl_up(x, o);
            if ((tid & 63) >= o) x += y;
        }
        if (tid == 63) wtot = x;
        __syncthreads();
        if (tid >= 64 && tid < 128) x += wtot;
        if (tid < 101) {
            int pr = x - v;                    // exclusive prefix; [100] = total
            g_pref[row][tid] = pr;
            if (tid < 100) g_offs[row][tid] = pr;   // init cursors each launch
        }
    }
}

// ---------------- K_scatter: parallel placement (512 blocks) ----------------
__global__ __launch_bounds__(BLK) void rank_scatter(const float* __restrict__ logits,
                                                    const float* __restrict__ labels) {
    const int bid = blockIdx.x;
    const int row = bid >> 3;
    const int x   = ((bid & 7) << 8) + threadIdx.x;
    const float la  = labels[(size_t)row * NN + x];
    const float lgx = logits[(size_t)row * NN + x];
    const int b = min(99, (int)(la * 100.0f));
    const int p = atomicAdd(&g_offs[row][b], 1);    // placement within bucket
    const float s = lgx * LOG2E;
    g_labs[row][p] = make_float2(la, s);
    g_Es[row][p]   = __builtin_amdgcn_exp2f(s);
    g_C[row][p]    = (b >= 1) ? g_pref[row][b - 1] : 0;
}

// ---------------- main work: side (LDS-staged, first) + tiles ----------------
__global__ __launch_bounds__(BLK) void rank_work() {
    const int bid = blockIdx.x;
    if (bid < SIDEBLKS) {
        // ---- side: bucket-distance <= 1 pairs, windows staged in LDS ----
        __shared__ float2 sLS[SWIN];
        __shared__ float  sE[SWIN];
        __shared__ int    sCs;
        __shared__ double sdw[4];
        const int row = bid >> 3;
        const int c0  = (bid & 7) << 8;
        const int tid = threadIdx.x;
        if (tid == 0) sCs = g_C[row][c0];
        __syncthreads();
        const int Cs  = sCs;
        const int len = c0 + 256 - Cs;
        for (int x = tid; x < len; x += BLK) {
            sLS[x] = g_labs[row][Cs + x];
            sE[x]  = g_Es[row][Cs + x];
        }
        __syncthreads();

        const int i    = c0 + tid;
        const int iloc = i - Cs;
        const float2 lsi = sLS[iloc];
        const float lai = lsi.x, si = lsi.y;
        const float Ei  = sE[iloc];
        const int wloc  = g_C[row][i] - Cs;

        float accL = 0.0f, accS = 0.0f;
        float p = 1.0f;
        int cnt8 = 0;
        for (int j = wloc; j < iloc; ++j) {
            float2 ls = sLS[j];
            float ld = lai - ls.x;
            bool valid = fabsf(ld) > TOLF;         // exact reference predicate
            float term = valid ? (Ei + sE[j]) : 1.0f;
            p *= term;
            if (++cnt8 == 8) { accL += __builtin_amdgcn_logf(p); p = 1.0f; cnt8 = 0; }
            float sh = (ld > 0.0f) ? si : ls.y;
            accS -= valid ? sh : 0.0f;
        }
        accL += __builtin_amdgcn_logf(p);

        double acc = (double)accL + (double)accS;
        for (int off = 32; off > 0; off >>= 1) acc += __shfl_down(acc, off);
        if ((tid & 63) == 0) sdw[tid >> 6] = acc;
        __syncthreads();
        if (tid == 0) g_partS[bid] = sdw[0] + sdw[1] + sdw[2] + sdw[3];
    } else {
        // ---- tiles: mask-free core (r13/r14/r15-proven) ----
        __shared__ __align__(16) float swin[256];
        __shared__ float swave[4];
        const int tb = bid - SIDEBLKS;
        const int row = tb / NTILE;                // block-uniform
        const int t = tb % NTILE;
        const int it = (t < 2) ? 0 : (t < 6) ? 1 : (t < 12) ? 2 : 3;
        const int jt = t - it * (it + 1);
        const int ibeg = it * 512, jbeg = jt * 256;

        float accL = 0.0f;
        const int Cmax = g_C[row][ibeg + 511];     // C monotone in position
        if (jbeg < Cmax) {
            for (int x = threadIdx.x; x < 64; x += BLK)
                ((float4*)swin)[x] = ((const float4*)&g_Es[row][jbeg])[x];
            __syncthreads();
            const int ia = ibeg + threadIdx.x;
            const int ib = ia + 256;
            const float invEa = __builtin_amdgcn_rcpf(g_Es[row][ia]);
            const float invEb = __builtin_amdgcn_rcpf(g_Es[row][ib]);
            int tripa = max(0, min(256, g_C[row][ia] - jbeg));
            int tripb = max(0, min(256, g_C[row][ib] - jbeg));   // >= tripa
            const int m16a = tripa & ~15;
            const int m16b = tripb & ~15;

            for (int jj = 0; jj < m16a; jj += 16) {
                const float4* q = (const float4*)&swin[jj];   // uniform: broadcast
                float4 w0 = q[0], w1 = q[1], w2 = q[2], w3 = q[3];
                float pa0 = 1.0f, pa1 = 1.0f, pb0 = 1.0f, pb1 = 1.0f;
                pa0 = fmaf(w0.x * invEa, pa0, pa0); pb0 = fmaf(w0.x * invEb, pb0, pb0);
                pa0 = fmaf(w0.y * invEa, pa0, pa0); pb0 = fmaf(w0.y * invEb, pb0, pb0);
                pa0 = fmaf(w0.z * invEa, pa0, pa0); pb0 = fmaf(w0.z * invEb, pb0, pb0);
                pa0 = fmaf(w0.w * invEa, pa0, pa0); pb0 = fmaf(w0.w * invEb, pb0, pb0);
                pa1 = fmaf(w1.x * invEa, pa1, pa1); pb1 = fmaf(w1.x * invEb, pb1, pb1);
                pa1 = fmaf(w1.y * invEa, pa1, pa1); pb1 = fmaf(w1.y * invEb, pb1, pb1);
                pa1 = fmaf(w1.z * invEa, pa1, pa1); pb1 = fmaf(w1.z * invEb, pb1, pb1);
                pa1 = fmaf(w1.w * invEa, pa1, pa1); pb1 = fmaf(w1.w * invEb, pb1, pb1);
                pa0 = fmaf(w2.x * invEa, pa0, pa0); pb0 = fmaf(w2.x * invEb, pb0, pb0);
                pa0 = fmaf(w2.y * invEa, pa0, pa0); pb0 = fmaf(w2.y * invEb, pb0, pb0);
                pa0 = fmaf(w2.z * invEa, pa0, pa0); pb0 = fmaf(w2.z * invEb, pb0, pb0);
                pa0 = fmaf(w2.w * invEa, pa0, pa0); pb0 = fmaf(w2.w * invEb, pb0, pb0);
                pa1 = fmaf(w3.x * invEa, pa1, pa1); pb1 = fmaf(w3.x * invEb, pb1, pb1);
                pa1 = fmaf(w3.y * invEa, pa1, pa1); pb1 = fmaf(w3.y * invEb, pb1, pb1);
                pa1 = fmaf(w3.z * invEa, pa1, pa1); pb1 = fmaf(w3.z * invEb, pb1, pb1);
                pa1 = fmaf(w3.w * invEa, pa1, pa1); pb1 = fmaf(w3.w * invEb, pb1, pb1);
                accL += __builtin_amdgcn_logf(pa0) + __builtin_amdgcn_logf(pa1)
                      + __builtin_amdgcn_logf(pb0) + __builtin_amdgcn_logf(pb1);
            }
            for (int jj = m16a; jj < m16b; jj += 16) {
                const float4* q = (const float4*)&swin[jj];
                float4 w0 = q[0], w1 = q[1], w2 = q[2], w3 = q[3];
                float pb0 = 1.0f, pb1 = 1.0f;
                pb0 = fmaf(w0.x * invEb, pb0, pb0);
                pb0 = fmaf(w0.y * invEb, pb0, pb0);
                pb0 = fmaf(w0.z * invEb, pb0, pb0);
                pb0 = fmaf(w0.w * invEb, pb0, pb0);
                pb1 = fmaf(w1.x * invEb, pb1, pb1);
                pb1 = fmaf(w1.y * invEb, pb1, pb1);
                pb1 = fmaf(w1.z * invEb, pb1, pb1);
                pb1 = fmaf(w1.w * invEb, pb1, pb1);
                pb0 = fmaf(w2.x * invEb, pb0, pb0);
                pb0 = fmaf(w2.y * invEb, pb0, pb0);
                pb0 = fmaf(w2.z * invEb, pb0, pb0);
                pb0 = fmaf(w2.w * invEb, pb0, pb0);
                pb1 = fmaf(w3.x * invEb, pb1, pb1);
                pb1 = fmaf(w3.y * invEb, pb1, pb1);
                pb1 = fmaf(w3.z * invEb, pb1, pb1);
                pb1 = fmaf(w3.w * invEb, pb1, pb1);
                accL += __builtin_amdgcn_logf(pb0) + __builtin_amdgcn_logf(pb1);
            }
            if (m16a < tripa) {
                float p0 = 1.0f, p1 = 1.0f;
#pragma unroll
                for (int u = 0; u < 8; ++u) {
                    float t0 = (m16a + u     < tripa) ? fmaf(swin[m16a + u],     invEa, 1.0f) : 1.0f;
                    float t1 = (m16a + 8 + u < tripa) ? fmaf(swin[m16a + 8 + u], invEa, 1.0f) : 1.0f;
                    p0 *= t0; p1 *= t1;
                }
                accL += __builtin_amdgcn_logf(p0) + __builtin_amdgcn_logf(p1);
            }
            if (m16b < tripb) {
                float p0 = 1.0f, p1 = 1.0f;
#pragma unroll
                for (int u = 0; u < 8; ++u) {
                    float t0 = (m16b + u     < tripb) ? fmaf(swin[m16b + u],     invEb, 1.0f) : 1.0f;
                    float t1 = (m16b + 8 + u < tripb) ? fmaf(swin[m16b + 8 + u], invEb, 1.0f) : 1.0f;
                    p0 *= t0; p1 *= t1;
                }
                accL += __builtin_amdgcn_logf(p0) + __builtin_amdgcn_logf(p1);
            }
        }
        for (int off = 32; off > 0; off >>= 1) accL += __shfl_down(accL, off);
        if ((threadIdx.x & 63) == 0) swave[threadIdx.x >> 6] = accL;
        __syncthreads();
        if (threadIdx.x == 0)
            g_part[tb] = swave[0] + swave[1] + swave[2] + swave[3];
    }
}

__global__ __launch_bounds__(BLK) void rank_final(float* __restrict__ out) {
    double acc = 0.0;
    for (int idx = threadIdx.x; idx < TILEBLKS; idx += BLK) acc += (double)g_part[idx];
    for (int idx = threadIdx.x; idx < SIDEBLKS; idx += BLK) acc += g_partS[idx];
    for (int off = 32; off > 0; off >>= 1) acc += __shfl_down(acc, off);
    __shared__ double sw[4];
    if ((threadIdx.x & 63) == 0) sw[threadIdx.x >> 6] = acc;
    __syncthreads();
    if (threadIdx.x == 0)
        out[0] = (float)((sw[0] + sw[1] + sw[2] + sw[3]) *
                         (-0.6931471805599453 / (double)BB));
}

extern "C" void kernel_launch(void* const* d_in, const int* in_sizes, int n_in,
                              void* d_out, int out_size, void* d_ws, size_t ws_size,
                              hipStream_t stream) {
    const float* logits = (const float*)d_in[0];
    const float* labels = (const float*)d_in[1];
    float* out = (float*)d_out;
    (void)in_sizes; (void)n_in; (void)out_size; (void)d_ws; (void)ws_size;

    rank_hist<<<BB, BLK, 0, stream>>>(labels);
    rank_scatter<<<SIDEBLKS, BLK, 0, stream>>>(logits, labels);
    rank_work<<<WGRID, BLK, 0, stream>>>();
    rank_final<<<1, BLK, 0, stream>>>(out);
}

// Round 21
// 26.642 us; speedup vs baseline: 6.9123x; 1.3076x over previous
//
#include <hip/hip_runtime.h>
#include <math.h>

// RankingLoss = mean over rows of sum_{pairs: lab_a-lab_b > TOL} lsig(lg_a-lg_b)
//
// lsig(x) = -ln2*log2(1 + 2^{s_lo - s_hi}),  s = logit*log2e,  E = 2^s.
// Rows reordered bucket-major by label (bucket width = TOL). For j < C_i
// (C_i = start of bucket b_i-1) pair guaranteed valid, i = high:
//   tile core: t = E_j*invE_i; p = fma(t,p,p); 512i x 256j tiles.
// r21 (single variable vs r15-champion, 27.1us): dense tile segments packed —
//   v2f loads straight from LDS (ds_read_b64 broadcast, no shuffles) +
//   __builtin_elementwise_fma -> v_pk_mul/v_pk_fma, ~1.1 instr/pair vs 2.
//   8-term log groups kept (t <= 2^13 -> 8 terms <= 2^105 < f32 max; 16 would
//   overflow). Everything else byte-identical to r15.
// Side pairs (C_i <= j < i): |ld|>TOL mask; (Ei+Ej) product + accS -= s_hi;
//   LDS-staged window; side blocks FIRST in grid.

#define NN 2048
#define BB 64
#define TOLF 0.01f
#define BLK 256
#define NTILE 20                         // i-tiles of 512: offsets it*(it+1)
#define TILEBLKS (BB * NTILE)            // 1280
#define SIDEBLKS (BB * 8)                // 512
#define WGRID (TILEBLKS + SIDEBLKS)      // 1792
#define SWIN 448                         // side LDS window capacity
#define LOG2E 1.4426950408889634f

typedef float v2f __attribute__((ext_vector_type(2)));

__device__ float2 g_labs[BB][NN];  // (label, s) bucket-major
__device__ float  g_Es[BB][NN];    // 2^s = e^logit
__device__ int    g_C[BB][NN];     // start of bucket b_i - 1
__device__ float  g_part[TILEBLKS];
__device__ double g_partS[SIDEBLKS];

// ---------------- preprocess: bucket reorder via LDS, coalesced export (r15) ----------------
__global__ __launch_bounds__(BLK) void rank_pre(const float* __restrict__ logits,
                                                const float* __restrict__ labels) {
    __shared__ float2 sls[NN];
    __shared__ float  sEv[NN];
    __shared__ int    sC[NN];
    __shared__ int    cnt[100], pref[101], offs[100];
    __shared__ int    wtot;
    const int row = blockIdx.x, tid = threadIdx.x;
    const float* lg = logits + (size_t)row * NN;
    const float* lb = labels + (size_t)row * NN;

    for (int x = tid; x < 100; x += BLK) { cnt[x] = 0; offs[x] = 0; }
    __syncthreads();

    int   myb[8];
    float myla[8], mylg[8];
#pragma unroll
    for (int q = 0; q < 8; ++q) {
        int x = tid + q * BLK;
        myla[q] = lb[x];
        mylg[q] = lg[x];
        myb[q]  = min(99, (int)(myla[q] * 100.0f));
        atomicAdd(&cnt[myb[q]], 1);
    }
    __syncthreads();
    {   // wave-parallel exclusive prefix over 100 counts
        int v = (tid < 100) ? cnt[tid] : 0;
        int x = v;
#pragma unroll
        for (int o = 1; o < 64; o <<= 1) {
            int y = __shfl_up(x, o);
            if ((tid & 63) >= o) x += y;
        }
        if (tid == 63) wtot = x;
        __syncthreads();
        if (tid >= 64 && tid < 128) x += wtot;
        if (tid < 101) pref[tid] = x - v;
    }
    __syncthreads();
#pragma unroll
    for (int q = 0; q < 8; ++q) {
        int b = myb[q];
        int p = pref[b] + atomicAdd(&offs[b], 1);
        float s = mylg[q] * LOG2E;
        sls[p] = make_float2(myla[q], s);
        sEv[p] = __builtin_amdgcn_exp2f(s);
        sC[p]  = (b >= 1) ? pref[b - 1] : 0;
    }
    __syncthreads();
    for (int x = tid; x < NN; x += BLK) {
        g_labs[row][x] = sls[x];
        g_Es[row][x]   = sEv[x];
        g_C[row][x]    = sC[x];
    }
}

// ---------------- main work: side (LDS-staged, first) + tiles ----------------
__global__ __launch_bounds__(BLK) void rank_work() {
    const int bid = blockIdx.x;
    if (bid < SIDEBLKS) {
        // ---- side: bucket-distance <= 1 pairs, windows staged in LDS (r15) ----
        __shared__ float2 sLS[SWIN];
        __shared__ float  sE[SWIN];
        __shared__ int    sCs;
        __shared__ double sdw[4];
        const int row = bid >> 3;
        const int c0  = (bid & 7) << 8;
        const int tid = threadIdx.x;
        if (tid == 0) sCs = g_C[row][c0];
        __syncthreads();
        const int Cs  = sCs;
        const int len = c0 + 256 - Cs;
        for (int x = tid; x < len; x += BLK) {
            sLS[x] = g_labs[row][Cs + x];
            sE[x]  = g_Es[row][Cs + x];
        }
        __syncthreads();

        const int i    = c0 + tid;
        const int iloc = i - Cs;
        const float2 lsi = sLS[iloc];
        const float lai = lsi.x, si = lsi.y;
        const float Ei  = sE[iloc];
        const int wloc  = g_C[row][i] - Cs;

        float accL = 0.0f, accS = 0.0f;
        float p = 1.0f;
        int cnt8 = 0;
        for (int j = wloc; j < iloc; ++j) {
            float2 ls = sLS[j];
            float ld = lai - ls.x;
            bool valid = fabsf(ld) > TOLF;         // exact reference predicate
            float term = valid ? (Ei + sE[j]) : 1.0f;
            p *= term;
            if (++cnt8 == 8) { accL += __builtin_amdgcn_logf(p); p = 1.0f; cnt8 = 0; }
            float sh = (ld > 0.0f) ? si : ls.y;
            accS -= valid ? sh : 0.0f;
        }
        accL += __builtin_amdgcn_logf(p);

        double acc = (double)accL + (double)accS;
        for (int off = 32; off > 0; off >>= 1) acc += __shfl_down(acc, off);
        if ((tid & 63) == 0) sdw[tid >> 6] = acc;
        __syncthreads();
        if (tid == 0) g_partS[bid] = sdw[0] + sdw[1] + sdw[2] + sdw[3];
    } else {
        // ---- tiles: mask-free core, dense segments PACKED (r21 change) ----
        __shared__ __align__(16) float swin[256];
        __shared__ float swave[4];
        const int tb = bid - SIDEBLKS;
        const int row = tb / NTILE;                // block-uniform
        const int t = tb % NTILE;
        const int it = (t < 2) ? 0 : (t < 6) ? 1 : (t < 12) ? 2 : 3;
        const int jt = t - it * (it + 1);
        const int ibeg = it * 512, jbeg = jt * 256;

        float accL = 0.0f;
        const int Cmax = g_C[row][ibeg + 511];     // C monotone in position
        if (jbeg < Cmax) {
            for (int x = threadIdx.x; x < 64; x += BLK)
                ((float4*)swin)[x] = ((const float4*)&g_Es[row][jbeg])[x];
            __syncthreads();
            const int ia = ibeg + threadIdx.x;
            const int ib = ia + 256;
            const float invEa = __builtin_amdgcn_rcpf(g_Es[row][ia]);
            const float invEb = __builtin_amdgcn_rcpf(g_Es[row][ib]);
            v2f iA; iA.x = invEa; iA.y = invEa;
            v2f iB; iB.x = invEb; iB.y = invEb;
            int tripa = max(0, min(256, g_C[row][ia] - jbeg));
            int tripb = max(0, min(256, g_C[row][ib] - jbeg));   // >= tripa
            const int m16a = tripa & ~15;
            const int m16b = tripb & ~15;

            // segment 1: both i's, packed v2f (v_pk_mul + v_pk_fma)
            for (int jj = 0; jj < m16a; jj += 16) {
                const v2f* qw = (const v2f*)&swin[jj];   // uniform: b64 broadcast
                v2f a0; a0.x = 1.0f; a0.y = 1.0f;
                v2f a1 = a0, b0 = a0, b1 = a0;
#pragma unroll
                for (int u = 0; u < 4; ++u) {
                    v2f w = qw[u];
                    a0 = __builtin_elementwise_fma(w * iA, a0, a0);
                    b0 = __builtin_elementwise_fma(w * iB, b0, b0);
                }
#pragma unroll
                for (int u = 4; u < 8; ++u) {
                    v2f w = qw[u];
                    a1 = __builtin_elementwise_fma(w * iA, a1, a1);
                    b1 = __builtin_elementwise_fma(w * iB, b1, b1);
                }
                // 8-term products per log (<= 2^105, safe; 16 would overflow)
                accL += __builtin_amdgcn_logf(a0.x * a0.y)
                      + __builtin_amdgcn_logf(a1.x * a1.y)
                      + __builtin_amdgcn_logf(b0.x * b0.y)
                      + __builtin_amdgcn_logf(b1.x * b1.y);
            }
            // segment 2: b only, packed
            for (int jj = m16a; jj < m16b; jj += 16) {
                const v2f* qw = (const v2f*)&swin[jj];
                v2f b0; b0.x = 1.0f; b0.y = 1.0f;
                v2f b1 = b0;
#pragma unroll
                for (int u = 0; u < 4; ++u)
                    b0 = __builtin_elementwise_fma(qw[u] * iB, b0, b0);
#pragma unroll
                for (int u = 4; u < 8; ++u)
                    b1 = __builtin_elementwise_fma(qw[u] * iB, b1, b1);
                accL += __builtin_amdgcn_logf(b0.x * b0.y)
                      + __builtin_amdgcn_logf(b1.x * b1.y);
            }
            // masked remainders (<=15 real terms each) — unchanged scalar
            if (m16a < tripa) {
                float p0 = 1.0f, p1 = 1.0f;
#pragma unroll
                for (int u = 0; u < 8; ++u) {
                    float t0 = (m16a + u     < tripa) ? fmaf(swin[m16a + u],     invEa, 1.0f) : 1.0f;
                    float t1 = (m16a + 8 + u < tripa) ? fmaf(swin[m16a + 8 + u], invEa, 1.0f) : 1.0f;
                    p0 *= t0; p1 *= t1;
                }
                accL += __builtin_amdgcn_logf(p0) + __builtin_amdgcn_logf(p1);
            }
            if (m16b < tripb) {
                float p0 = 1.0f, p1 = 1.0f;
#pragma unroll
                for (int u = 0; u < 8; ++u) {
                    float t0 = (m16b + u     < tripb) ? fmaf(swin[m16b + u],     invEb, 1.0f) : 1.0f;
                    float t1 = (m16b + 8 + u < tripb) ? fmaf(swin[m16b + 8 + u], invEb, 1.0f) : 1.0f;
                    p0 *= t0; p1 *= t1;
                }
                accL += __builtin_amdgcn_logf(p0) + __builtin_amdgcn_logf(p1);
            }
        }
        for (int off = 32; off > 0; off >>= 1) accL += __shfl_down(accL, off);
        if ((threadIdx.x & 63) == 0) swave[threadIdx.x >> 6] = accL;
        __syncthreads();
        if (threadIdx.x == 0)
            g_part[tb] = swave[0] + swave[1] + swave[2] + swave[3];
    }
}

__global__ __launch_bounds__(BLK) void rank_final(float* __restrict__ out) {
    double acc = 0.0;
    for (int idx = threadIdx.x; idx < TILEBLKS; idx += BLK) acc += (double)g_part[idx];
    for (int idx = threadIdx.x; idx < SIDEBLKS; idx += BLK) acc += g_partS[idx];
    for (int off = 32; off > 0; off >>= 1) acc += __shfl_down(acc, off);
    __shared__ double sw[4];
    if ((threadIdx.x & 63) == 0) sw[threadIdx.x >> 6] = acc;
    __syncthreads();
    if (threadIdx.x == 0)
        out[0] = (float)((sw[0] + sw[1] + sw[2] + sw[3]) *
                         (-0.6931471805599453 / (double)BB));
}

extern "C" void kernel_launch(void* const* d_in, const int* in_sizes, int n_in,
                              void* d_out, int out_size, void* d_ws, size_t ws_size,
                              hipStream_t stream) {
    const float* logits = (const float*)d_in[0];
    const float* labels = (const float*)d_in[1];
    float* out = (float*)d_out;
    (void)in_sizes; (void)n_in; (void)out_size; (void)d_ws; (void)ws_size;

    rank_pre<<<BB, BLK, 0, stream>>>(logits, labels);
    rank_work<<<WGRID, BLK, 0, stream>>>();
    rank_final<<<1, BLK, 0, stream>>>(out);
}